// Round 1
// baseline (588.100 us; speedup 1.0000x reference)
//
#include <hip/hip_runtime.h>
#include <hip/hip_bf16.h>
#include <stdint.h>

// SimLinear: C[50,8192] = x[50,8192] @ W[8192,8192]^T + bias
// Memory-bound (stream W = 268 MB once). bf16 MFMA so compute stays off the
// critical path (fp32 VALU would sit exactly at the roofline corner).

#define K_DIM   8192
#define O_DIM   8192
#define BATCH   50
#define KSPLIT  8      // 256 o-tiles x 8 k-chunks = 2048 WGs (8/CU nominal)

typedef __attribute__((ext_vector_type(8)))  __bf16 bf16x8;
typedef __attribute__((ext_vector_type(16))) float  f32x16;
typedef __attribute__((ext_vector_type(4)))  int    i32x4;

// Pack two fp32 -> one dword of two bf16 (round-half-up): add 0x8000 to the
// fp32 bits, then v_perm_b32 extracts the two high halves. 3 VALU per pair.
__device__ __forceinline__ unsigned bfpair(float a, float b) {
    unsigned ua = __float_as_uint(a) + 0x8000u;
    unsigned ub = __float_as_uint(b) + 0x8000u;
    // dst bytes: [ua.b2, ua.b3, ub.b2, ub.b3] -> lo16 = bf16(a), hi16 = bf16(b)
    return __builtin_amdgcn_perm(ub, ua, 0x07060302u);
}

__device__ __forceinline__ bf16x8 pack8(float4 lo, float4 hi) {
    i32x4 p;
    p.x = (int)bfpair(lo.x, lo.y);
    p.y = (int)bfpair(lo.z, lo.w);
    p.z = (int)bfpair(hi.x, hi.y);
    p.w = (int)bfpair(hi.z, hi.w);
    return __builtin_bit_cast(bf16x8, p);
}

// out[b*8192+o] = bias[o]  (runs first; atomics accumulate on top)
__global__ void simlinear_init_bias(const float* __restrict__ bias,
                                    float* __restrict__ out) {
    int i = blockIdx.x * 256 + threadIdx.x;
    if (i < BATCH * O_DIM) out[i] = bias[i & (O_DIM - 1)];
}

// Each WG: one 32-row o-tile, one 1024-wide k-chunk. 4 waves split the chunk.
// Per wave per k-step (k=16): A = W[32 o x 16 k], B = x^T[16 k x {b-tile}].
// MFMA 32x32x16 bf16 operand layout: A[m=lane&31][k=(lane>>5)*8+j],
// B[k=(lane>>5)*8+j][n=lane&31] -> each lane loads 8 consecutive k (2 float4).
// C/D layout (measured, guide §3): col=lane&31, row=(reg&3)+8*(reg>>2)+4*(lane>>5).
__global__ __launch_bounds__(256, 4) void simlinear_mfma(
        const float* __restrict__ X,     // [50, 8192]
        const float* __restrict__ W,     // [8192, 8192]
        float* __restrict__ out) {       // [50, 8192]
    __shared__ float red[4 * 2048];      // 32 KB: per-wave partial tiles

    const int tid   = threadIdx.x;
    const int wave  = tid >> 6;
    const int lane  = tid & 63;
    const int l31   = lane & 31;
    const int half  = lane >> 5;
    const int otile = blockIdx.x & 255;
    const int ks    = blockIdx.x >> 8;
    const int obase = otile * 32;
    const int k0    = ks * (K_DIM / KSPLIT) + wave * (K_DIM / KSPLIT / 4); // 256 k per wave

    const float* wp  = W + (size_t)(obase + l31) * K_DIM + k0 + half * 8;
    const float* xp0 = X + (size_t)l31 * K_DIM + k0 + half * 8;           // b = l31
    const int    b1  = l31 + 32;                                          // b-tile 1
    const float* xp1 = X + (size_t)b1 * K_DIM + k0 + half * 8;
    const bool   v1  = (b1 < BATCH);

    f32x16 acc0 = {};
    f32x16 acc1 = {};
    const float4 zero4 = {0.f, 0.f, 0.f, 0.f};

    #pragma unroll 2
    for (int s = 0; s < 16; ++s) {       // 16 k-steps of 16 -> 256 k
        const float4 a0  = *(const float4*)(wp  + s * 16);
        const float4 a1  = *(const float4*)(wp  + s * 16 + 4);
        const float4 x0a = *(const float4*)(xp0 + s * 16);
        const float4 x0b = *(const float4*)(xp0 + s * 16 + 4);
        const float4 x1a = v1 ? *(const float4*)(xp1 + s * 16)     : zero4;
        const float4 x1b = v1 ? *(const float4*)(xp1 + s * 16 + 4) : zero4;

        bf16x8 af  = pack8(a0, a1);
        bf16x8 bf0 = pack8(x0a, x0b);
        bf16x8 bf1 = pack8(x1a, x1b);

        acc0 = __builtin_amdgcn_mfma_f32_32x32x16_bf16(af, bf0, acc0, 0, 0, 0);
        acc1 = __builtin_amdgcn_mfma_f32_32x32x16_bf16(af, bf1, acc1, 0, 0, 0);
    }

    // Stage per-wave 32(o) x 64(b) partial tile into LDS.
    // idx = o_local*64 + b. Fixed reg: lanes 0..31 hit banks 0..31 (conflict-
    // free); the two lane-halves alias 2-way (free, m136).
    float* myred = red + wave * 2048;
    #pragma unroll
    for (int r = 0; r < 16; ++r) {
        int o_local = (r & 3) + 8 * (r >> 2) + 4 * half;
        myred[o_local * 64 + l31]      = acc0[r];
        myred[o_local * 64 + 32 + l31] = acc1[r];
    }
    __syncthreads();

    // Cross-wave reduce + one device-scope fp32 atomic per valid output.
    #pragma unroll
    for (int i = tid; i < 2048; i += 256) {
        float s = red[i] + red[2048 + i] + red[4096 + i] + red[6144 + i];
        int b = i & 63;
        int o = obase + (i >> 6);
        if (b < BATCH)
            unsafeAtomicAdd(out + (size_t)b * O_DIM + o, s);  // global_atomic_add_f32
    }
}

extern "C" void kernel_launch(void* const* d_in, const int* in_sizes, int n_in,
                              void* d_out, int out_size, void* d_ws, size_t ws_size,
                              hipStream_t stream) {
    const float* x    = (const float*)d_in[0];   // [50, 8192]
    const float* w    = (const float*)d_in[1];   // [8192, 8192]
    const float* bias = (const float*)d_in[2];   // [8192]
    float* out = (float*)d_out;                  // [50, 8192]

    simlinear_init_bias<<<(BATCH * O_DIM + 255) / 256, 256, 0, stream>>>(bias, out);
    simlinear_mfma<<<256 * KSPLIT, 256, 0, stream>>>(x, w, out);
}

// Round 2
// 460.341 us; speedup vs baseline: 1.2775x; 1.2775x over previous
//
#include <hip/hip_runtime.h>
#include <hip/hip_bf16.h>
#include <stdint.h>

// SimLinear: C[50,8192] = x[50,8192] @ W[8192,8192]^T + bias
// BW-bound: stream W (268 MB) once. R1: LDS-staged W via global_load_lds
// (contiguous 1 KB per instr -> sequential DRAM streams), coalesced atomic
// epilogue (R0's scattered 4B atomics caused 100 MB of 32B-sector writes).

#define K_DIM   8192
#define O_DIM   8192
#define BATCH   50
#define KSPLIT  4
#define BK      256                      // fp32 k per tile (1 KB per row)
#define NTILE   (K_DIM / KSPLIT / BK)    // 8 tiles per WG
#define RSTRIDE 260                      // 256 + 4 dword pad: l31*260 % 32 = 4*l31 -> optimal 8-phase b128
#define REDS    33                       // reduce b-stride (pad +1)
#define REDW    (64 * REDS)              // 2112 floats per wave

typedef __attribute__((ext_vector_type(8)))  __bf16 bf16x8;
typedef __attribute__((ext_vector_type(16))) float  f32x16;
typedef __attribute__((ext_vector_type(4)))  int    i32x4;

typedef const __attribute__((address_space(1))) void* gptr_t;
typedef __attribute__((address_space(3)))       void* lptr_t;

// fp32 pair -> dword of 2 bf16, round-half-up: +0x8000 then take high halves.
__device__ __forceinline__ unsigned bfpair(float a, float b) {
    unsigned ua = __float_as_uint(a) + 0x8000u;
    unsigned ub = __float_as_uint(b) + 0x8000u;
    return __builtin_amdgcn_perm(ub, ua, 0x07060302u);
}

__device__ __forceinline__ bf16x8 pack8(float4 lo, float4 hi) {
    i32x4 p;
    p.x = (int)bfpair(lo.x, lo.y);
    p.y = (int)bfpair(lo.z, lo.w);
    p.z = (int)bfpair(hi.x, hi.y);
    p.w = (int)bfpair(hi.z, hi.w);
    return __builtin_bit_cast(bf16x8, p);
}

// out[b,o] = bias[o]; atomics accumulate partial sums on top.
__global__ void simlinear_init_bias(const float* __restrict__ bias,
                                    float* __restrict__ out) {
    int i = blockIdx.x * 256 + threadIdx.x;
    if (i < BATCH * O_DIM) out[i] = bias[i & (O_DIM - 1)];
}

// WG: o-tile of 32 W-rows, k-chunk of 2048. Loop 8 tiles of BK=256:
//   stage W[32 x 256] fp32 into LDS (global_load_lds, 1 KB contiguous/instr),
//   4 waves split the 16 k-steps (wave w -> steps 4w..4w+3, a clean k-partition),
//   x fragments straight from global (L2-resident, 1.6 MB).
// MFMA 32x32x16 bf16; C/D: col=lane&31, row=(reg&3)+8*(reg>>2)+4*(lane>>5).
__global__ __launch_bounds__(256, 4) void simlinear_mfma(
        const float* __restrict__ X,     // [50, 8192]
        const float* __restrict__ W,     // [8192, 8192]
        float* __restrict__ out) {       // [50, 8192]
    __shared__ float lds[4 * REDW];      // 8448 dw = 33 KB; staging needs 32*260=8320 dw

    const int tid   = threadIdx.x;
    const int wave  = tid >> 6;
    const int lane  = tid & 63;
    const int l31   = lane & 31;
    const int half  = lane >> 5;
    const int otile = blockIdx.x & 255;
    const int ks    = blockIdx.x >> 8;
    const int obase = otile * 32;
    const int k0    = ks * (K_DIM / KSPLIT);   // 2048-wide chunk

    // Staging: wave stages rows wave*8 .. wave*8+7; lane supplies +16B*lane.
    const float* wbase = W + (size_t)(obase + wave * 8) * K_DIM + k0 + lane * 4;
    const float* xb0   = X + (size_t)l31 * K_DIM + k0 + half * 8;         // b = l31 (<32<50, valid)
    const float* xb1   = X + (size_t)(l31 + 32) * K_DIM + k0 + half * 8;  // b = l31+32
    const bool   v1    = (l31 + 32 < BATCH);                              // l31 < 18

    f32x16 acc0 = {};
    f32x16 acc1 = {};
    const float4 zero4 = {0.f, 0.f, 0.f, 0.f};

    for (int t = 0; t < NTILE; ++t) {
        // ---- stage tile t: 32 rows x 1 KB ----
        #pragma unroll
        for (int j = 0; j < 8; ++j) {
            const float* gp = wbase + (size_t)j * K_DIM + t * BK;
            __builtin_amdgcn_global_load_lds((gptr_t)gp,
                (lptr_t)&lds[(wave * 8 + j) * RSTRIDE], 16, 0, 0);
        }
        __syncthreads();   // compiler drains vmcnt(0) here; 4 WGs/CU overlap the stall

        // ---- compute: wave w does k-steps 4w..4w+3 of this tile ----
        #pragma unroll
        for (int j = 0; j < 4; ++j) {
            const int s    = wave * 4 + j;
            const int koff = s * 16 + half * 8;

            const float4 a0 = *(const float4*)&lds[l31 * RSTRIDE + koff];
            const float4 a1 = *(const float4*)&lds[l31 * RSTRIDE + koff + 4];

            const float* xp = xb0 + t * BK + s * 16;
            const float4 x0a = *(const float4*)(xp);
            const float4 x0b = *(const float4*)(xp + 4);
            const float* xq = xb1 + t * BK + s * 16;
            const float4 x1a = v1 ? *(const float4*)(xq)     : zero4;
            const float4 x1b = v1 ? *(const float4*)(xq + 4) : zero4;

            bf16x8 af  = pack8(a0, a1);
            bf16x8 bf0 = pack8(x0a, x0b);
            bf16x8 bf1 = pack8(x1a, x1b);

            acc0 = __builtin_amdgcn_mfma_f32_32x32x16_bf16(af, bf0, acc0, 0, 0, 0);
            acc1 = __builtin_amdgcn_mfma_f32_32x32x16_bf16(af, bf1, acc1, 0, 0, 0);
        }
        __syncthreads();   // tile consumed; safe to overwrite LDS
    }

    // ---- cross-wave reduce in LDS: red[wave][b*33 + o], conflict-free both ways ----
    float* myred = lds + wave * REDW;
    #pragma unroll
    for (int r = 0; r < 16; ++r) {
        int o_local = (r & 3) + 8 * (r >> 2) + 4 * half;
        myred[l31 * REDS + o_local]        = acc0[r];
        myred[(l31 + 32) * REDS + o_local] = acc1[r];
    }
    __syncthreads();

    // ---- sum 4 waves + coalesced atomic (per instr: o-contiguous 128 B runs) ----
    #pragma unroll
    for (int i = tid; i < 2048; i += 256) {
        int b = i >> 5;
        int o = i & 31;
        float s = lds[0 * REDW + b * REDS + o] + lds[1 * REDW + b * REDS + o]
                + lds[2 * REDW + b * REDS + o] + lds[3 * REDW + b * REDS + o];
        if (b < BATCH)
            unsafeAtomicAdd(out + (size_t)b * O_DIM + obase + o, s);
    }
}

extern "C" void kernel_launch(void* const* d_in, const int* in_sizes, int n_in,
                              void* d_out, int out_size, void* d_ws, size_t ws_size,
                              hipStream_t stream) {
    const float* x    = (const float*)d_in[0];
    const float* w    = (const float*)d_in[1];
    const float* bias = (const float*)d_in[2];
    float* out = (float*)d_out;

    simlinear_init_bias<<<(BATCH * O_DIM + 255) / 256, 256, 0, stream>>>(bias, out);
    simlinear_mfma<<<256 * KSPLIT, 256, 0, stream>>>(x, w, out);
}

// Round 3
// 380.065 us; speedup vs baseline: 1.5474x; 1.2112x over previous
//
#include <hip/hip_runtime.h>
#include <hip/hip_bf16.h>
#include <stdint.h>

// SimLinear: C[50,8192] = x[50,8192] @ W[8192,8192]^T + bias
// R3: fix DRAM channel collapse. R0/R2 bursts touched W rows at 32 KB stride
// with tiny per-row chunks (64 B / 1 KB) -> low address bits (channel select)
// nearly constant across the burst -> 0.83 / 1.3 TB/s. R3 stages 4 KB
// contiguous per row per tile (BK=1024 fp32), full K per WG (no atomics),
// x pre-packed to bf16 B-fragment order in d_ws (read-only from L2).

#define K_DIM  8192
#define O_DIM  8192
#define BATCH  50
#define BPAD   64                 // padded batch (b>=50 zeroed in packed x)
#define ROWS   16                 // W rows (outputs) per WG
#define BK     1024               // fp32 k per tile -> 4 KB contiguous per row
#define NT     (K_DIM / BK)       // 8 tiles, full K per WG
#define RS     (BK + 4)           // LDS row stride (dwords): pad keeps b128 2-way max
#define NWG    (O_DIM / ROWS)     // 512 WGs -> 2 per CU
#define XP_ELEMS ((size_t)(K_DIM / 8) * BPAD * 8)   // bf16 elems = 512K (1 MiB)

typedef __attribute__((ext_vector_type(8)))  __bf16 bf16x8;
typedef __attribute__((ext_vector_type(4)))  float  f32x4;
typedef __attribute__((ext_vector_type(4)))  int    i32x4;

typedef const __attribute__((address_space(1))) void* gptr_t;
typedef __attribute__((address_space(3)))       void* lptr_t;

// fp32 pair -> dword of two bf16 (round-half-up): +0x8000 then high halves.
__device__ __forceinline__ unsigned bfpair(float a, float b) {
    unsigned ua = __float_as_uint(a) + 0x8000u;
    unsigned ub = __float_as_uint(b) + 0x8000u;
    return __builtin_amdgcn_perm(ub, ua, 0x07060302u);  // [a.hi16, b.hi16]
}

__device__ __forceinline__ bf16x8 pack8(float4 lo, float4 hi) {
    i32x4 p;
    p.x = (int)bfpair(lo.x, lo.y);
    p.y = (int)bfpair(lo.z, lo.w);
    p.z = (int)bfpair(hi.x, hi.y);
    p.w = (int)bfpair(hi.z, hi.w);
    return __builtin_bit_cast(bf16x8, p);
}

// Pack x[50,8192] fp32 -> XP[k/8][b(64)][8] bf16 (B-fragment octet order,
// b>=50 zero). Thread i: b = i&63, ko = i>>6; writes 16 B at XP + i*8.
__global__ void pack_x(const float* __restrict__ X,
                       __hip_bfloat16* __restrict__ XP) {
    int i  = blockIdx.x * 256 + threadIdx.x;     // [0, 65536)
    int b  = i & 63;
    int ko = i >> 6;                             // k-octet [0, 1024)
    float4 z = {0.f, 0.f, 0.f, 0.f};
    float4 lo = z, hi = z;
    if (b < BATCH) {
        const float* xp = X + (size_t)b * K_DIM + (size_t)ko * 8;
        lo = *(const float4*)xp;
        hi = *(const float4*)(xp + 4);
    }
    *(bf16x8*)(XP + (size_t)i * 8) = pack8(lo, hi);
}

// WG: 16 W rows x full K. Per tile: stage [16 rows x 4 KB] via global_load_lds
// (1 KB contiguous per instr, 4 consecutive instrs per row -> 4 KB streams).
// Waves split the 32 k-steps (8 each). MFMA 16x16x32 bf16:
//   A[m=lane&15][k=(lane>>4)*8+j]  (from LDS fp32, packed per use)
//   B[k=(lane>>4)*8+j][n=lane&15]  (raw bf16x8 from packed x)
//   C/D: col=lane&15, row=(lane>>4)*4+reg
// Epilogue: cross-wave k-reduce in LDS, direct store + bias (no atomics).
template<bool PACKED>
__global__ __launch_bounds__(256, 2) void simlinear_mfma(
        const float* __restrict__ X,
        const float* __restrict__ W,
        const __hip_bfloat16* __restrict__ XP,
        const float* __restrict__ bias,
        float* __restrict__ out) {
    __shared__ float lds[ROWS * RS];             // 16*1028 dw = 65792 B

    const int tid   = threadIdx.x;
    const int wave  = tid >> 6;
    const int lane  = tid & 63;
    const int l15   = lane & 15;
    const int q     = lane >> 4;                 // k-octet within step
    const int obase = blockIdx.x * ROWS;

    // Wave w stages rows 4w..4w+3; lane contributes 16 B at +lane*16.
    const float* wrow = W + (size_t)(obase + wave * 4) * K_DIM + lane * 4;

    f32x4 acc[4] = {};                           // 4 b-groups x 4 f32

    for (int t = 0; t < NT; ++t) {
        // ---- stage tile: 16 rows x 4 KB (4x 1 KB consecutive per row) ----
        #pragma unroll
        for (int r = 0; r < 4; ++r) {
            #pragma unroll
            for (int c = 0; c < 4; ++c) {
                __builtin_amdgcn_global_load_lds(
                    (gptr_t)(wrow + (size_t)r * K_DIM + t * BK + c * 256),
                    (lptr_t)&lds[(wave * 4 + r) * RS + c * 256], 16, 0, 0);
            }
        }
        __syncthreads();

        // ---- compute: wave w -> k-steps w*8 .. w*8+7 of this tile ----
        #pragma unroll
        for (int s = 0; s < 8; ++s) {
            const int S    = wave * 8 + s;       // step in tile [0,32)
            const int koff = S * 32 + q * 8;     // dw offset in row
            float4 a0 = *(const float4*)&lds[l15 * RS + koff];
            float4 a1 = *(const float4*)&lds[l15 * RS + koff + 4];
            bf16x8 af = pack8(a0, a1);
            const int ko = t * (BK / 8) + S * 4 + q;   // global k-octet
            #pragma unroll
            for (int g = 0; g < 4; ++g) {
                bf16x8 bf;
                if (PACKED) {
                    bf = *(const bf16x8*)(XP + ((size_t)ko * BPAD + g * 16 + l15) * 8);
                } else {
                    const int b = g * 16 + l15;
                    float4 z = {0.f, 0.f, 0.f, 0.f}, x0 = z, x1 = z;
                    if (b < BATCH) {
                        const float* xp = X + (size_t)b * K_DIM + (size_t)ko * 8;
                        x0 = *(const float4*)xp;
                        x1 = *(const float4*)(xp + 4);
                    }
                    bf = pack8(x0, x1);
                }
                acc[g] = __builtin_amdgcn_mfma_f32_16x16x32_bf16(af, bf, acc[g], 0, 0, 0);
            }
        }
        __syncthreads();                          // tile consumed
    }

    // ---- cross-wave reduce: red[w][b*16+m], reuse LDS ----
    #pragma unroll
    for (int g = 0; g < 4; ++g) {
        #pragma unroll
        for (int r = 0; r < 4; ++r) {
            // lane holds C[row = q*4+r][col = g*16+l15] -> (m = q*4+r, b = g*16+l15)
            lds[wave * 1024 + (g * 16 + l15) * 16 + (q * 4 + r)] = acc[g][r];
        }
    }
    __syncthreads();

    #pragma unroll
    for (int it = 0; it < 4; ++it) {
        const int i = it * 256 + tid;            // [0,1024): b = i>>4, m = i&15
        const int b = i >> 4;
        const int m = i & 15;
        float s = lds[i] + lds[1024 + i] + lds[2048 + i] + lds[3072 + i];
        if (b < BATCH)
            out[(size_t)b * O_DIM + obase + m] = s + bias[obase + m];
    }
}

extern "C" void kernel_launch(void* const* d_in, const int* in_sizes, int n_in,
                              void* d_out, int out_size, void* d_ws, size_t ws_size,
                              hipStream_t stream) {
    const float* x    = (const float*)d_in[0];
    const float* w    = (const float*)d_in[1];
    const float* bias = (const float*)d_in[2];
    float* out = (float*)d_out;
    __hip_bfloat16* xp = (__hip_bfloat16*)d_ws;

    const bool packed = ws_size >= XP_ELEMS * sizeof(__hip_bfloat16);
    if (packed) {
        pack_x<<<(K_DIM / 8) * BPAD / 256, 256, 0, stream>>>(x, xp);
        simlinear_mfma<true><<<NWG, 256, 0, stream>>>(x, w, xp, bias, out);
    } else {
        simlinear_mfma<false><<<NWG, 256, 0, stream>>>(x, w, xp, bias, out);
    }
}

// Round 4
// 377.171 us; speedup vs baseline: 1.5592x; 1.0077x over previous
//
#include <hip/hip_runtime.h>
#include <hip/hip_bf16.h>
#include <stdint.h>

// SimLinear: C[50,8192] = x[50,8192] @ W[8192,8192]^T + bias
// R4: replace global_load_lds staging (LDS-DMA path caps ~2 TB/s at HBM
// latency: small outstanding window x ~1200 cyc loaded latency) with plain
// global_load_dwordx4 -> VGPR -> ds_write_b128. Plain loads pipeline 16-deep
// per wave on vmcnt -> 64 KB+/CU in flight -> BW-limited, not latency-limited.
// Everything else (packed-x B operand, MFMA 16x16x32, epilogue) as R3.

#define K_DIM  8192
#define O_DIM  8192
#define BATCH  50
#define BPAD   64                 // padded batch (b>=50 zeroed in packed x)
#define ROWS   16                 // W rows (outputs) per WG
#define BK     1024               // fp32 k per tile -> 4 KB contiguous per row
#define NT     (K_DIM / BK)       // 8 tiles, full K per WG
#define RS     (BK + 4)           // LDS row stride (dw): 2-way max on b128 r/w
#define NWG    (O_DIM / ROWS)     // 512 WGs -> 2 per CU
#define XP_ELEMS ((size_t)(K_DIM / 8) * BPAD * 8)   // bf16 elems (1 MiB)

typedef __attribute__((ext_vector_type(8)))  __bf16 bf16x8;
typedef __attribute__((ext_vector_type(4)))  float  f32x4;
typedef __attribute__((ext_vector_type(4)))  int    i32x4;

// fp32 pair -> dword of two bf16 (round-half-up): +0x8000 then high halves.
__device__ __forceinline__ unsigned bfpair(float a, float b) {
    unsigned ua = __float_as_uint(a) + 0x8000u;
    unsigned ub = __float_as_uint(b) + 0x8000u;
    return __builtin_amdgcn_perm(ub, ua, 0x07060302u);  // [a.hi16, b.hi16]
}

__device__ __forceinline__ bf16x8 pack8(float4 lo, float4 hi) {
    i32x4 p;
    p.x = (int)bfpair(lo.x, lo.y);
    p.y = (int)bfpair(lo.z, lo.w);
    p.z = (int)bfpair(hi.x, hi.y);
    p.w = (int)bfpair(hi.z, hi.w);
    return __builtin_bit_cast(bf16x8, p);
}

// Pack x[50,8192] fp32 -> XP[k/8][b(64)][8] bf16 (B-fragment octet order,
// b>=50 zero). Thread i: b = i&63, ko = i>>6; writes 16 B at XP + i*8.
__global__ void pack_x(const float* __restrict__ X,
                       __hip_bfloat16* __restrict__ XP) {
    int i  = blockIdx.x * 256 + threadIdx.x;     // [0, 65536)
    int b  = i & 63;
    int ko = i >> 6;                             // k-octet [0, 1024)
    float4 z = {0.f, 0.f, 0.f, 0.f};
    float4 lo = z, hi = z;
    if (b < BATCH) {
        const float* xp = X + (size_t)b * K_DIM + (size_t)ko * 8;
        lo = *(const float4*)xp;
        hi = *(const float4*)(xp + 4);
    }
    *(bf16x8*)(XP + (size_t)i * 8) = pack8(lo, hi);
}

// WG: 16 W rows x full K. Per tile (BK=1024): wave w loads rows 4w..4w+3
// (4x 1 KB coalesced dwordx4 per row, 16 loads -> 64 VGPRs, vmcnt-pipelined),
// ds_write_b128 to LDS, barrier, compute (wave w -> k-steps 8w..8w+7):
//   A[m=lane&15][k=(lane>>4)*8+j]  from LDS fp32, packed per use
//   B[k][n=lane&15]                raw bf16x8 from packed x (L2-resident)
//   C/D: col=lane&15, row=(lane>>4)*4+reg
// Epilogue: cross-wave k-reduce in LDS, direct store + bias (no atomics).
template<bool PACKED>
__global__ __launch_bounds__(256, 2) void simlinear_mfma(
        const float* __restrict__ X,
        const float* __restrict__ W,
        const __hip_bfloat16* __restrict__ XP,
        const float* __restrict__ bias,
        float* __restrict__ out) {
    __shared__ float lds[ROWS * RS];             // 16*1028 dw = 65792 B

    const int tid   = threadIdx.x;
    const int wave  = tid >> 6;
    const int lane  = tid & 63;
    const int l15   = lane & 15;
    const int q     = lane >> 4;                 // k-octet within step
    const int obase = blockIdx.x * ROWS;

    const float* wrow = W + (size_t)(obase + wave * 4) * K_DIM + lane * 4;

    f32x4 acc[4] = {};                           // 4 b-groups x 4 f32

    for (int t = 0; t < NT; ++t) {
        // ---- stage tile: 4 rows/wave x 4 KB, plain loads -> VGPRs ----
        float4 st[16];
        #pragma unroll
        for (int r = 0; r < 4; ++r)
            #pragma unroll
            for (int c = 0; c < 4; ++c)
                st[r * 4 + c] =
                    *(const float4*)(wrow + (size_t)r * K_DIM + t * BK + c * 256);
        // ---- VGPR -> LDS (b128, 2-way max bank aliasing = free) ----
        #pragma unroll
        for (int r = 0; r < 4; ++r)
            #pragma unroll
            for (int c = 0; c < 4; ++c)
                *(float4*)&lds[(wave * 4 + r) * RS + c * 256 + lane * 4] =
                    st[r * 4 + c];
        __syncthreads();

        // ---- compute: wave w -> k-steps w*8 .. w*8+7 of this tile ----
        #pragma unroll
        for (int s = 0; s < 8; ++s) {
            const int S    = wave * 8 + s;       // step in tile [0,32)
            const int koff = S * 32 + q * 8;     // dw offset in row
            float4 a0 = *(const float4*)&lds[l15 * RS + koff];
            float4 a1 = *(const float4*)&lds[l15 * RS + koff + 4];
            bf16x8 af = pack8(a0, a1);
            const int ko = t * (BK / 8) + S * 4 + q;   // global k-octet
            #pragma unroll
            for (int g = 0; g < 4; ++g) {
                bf16x8 bf;
                if (PACKED) {
                    bf = *(const bf16x8*)(XP + ((size_t)ko * BPAD + g * 16 + l15) * 8);
                } else {
                    const int b = g * 16 + l15;
                    float4 z = {0.f, 0.f, 0.f, 0.f}, x0 = z, x1 = z;
                    if (b < BATCH) {
                        const float* xp = X + (size_t)b * K_DIM + (size_t)ko * 8;
                        x0 = *(const float4*)xp;
                        x1 = *(const float4*)(xp + 4);
                    }
                    bf = pack8(x0, x1);
                }
                acc[g] = __builtin_amdgcn_mfma_f32_16x16x32_bf16(af, bf, acc[g], 0, 0, 0);
            }
        }
        __syncthreads();                          // tile consumed
    }

    // ---- cross-wave reduce: red[w][b*16+m], reuse LDS ----
    #pragma unroll
    for (int g = 0; g < 4; ++g) {
        #pragma unroll
        for (int r = 0; r < 4; ++r) {
            // lane holds C[row = q*4+r][col = g*16+l15] -> (m = q*4+r, b = g*16+l15)
            lds[wave * 1024 + (g * 16 + l15) * 16 + (q * 4 + r)] = acc[g][r];
        }
    }
    __syncthreads();

    #pragma unroll
    for (int it = 0; it < 4; ++it) {
        const int i = it * 256 + tid;            // [0,1024): b = i>>4, m = i&15
        const int b = i >> 4;
        const int m = i & 15;
        float s = lds[i] + lds[1024 + i] + lds[2048 + i] + lds[3072 + i];
        if (b < BATCH)
            out[(size_t)b * O_DIM + obase + m] = s + bias[obase + m];
    }
}

extern "C" void kernel_launch(void* const* d_in, const int* in_sizes, int n_in,
                              void* d_out, int out_size, void* d_ws, size_t ws_size,
                              hipStream_t stream) {
    const float* x    = (const float*)d_in[0];
    const float* w    = (const float*)d_in[1];
    const float* bias = (const float*)d_in[2];
    float* out = (float*)d_out;
    __hip_bfloat16* xp = (__hip_bfloat16*)d_ws;

    const bool packed = ws_size >= XP_ELEMS * sizeof(__hip_bfloat16);
    if (packed) {
        pack_x<<<(K_DIM / 8) * BPAD / 256, 256, 0, stream>>>(x, xp);
        simlinear_mfma<true><<<NWG, 256, 0, stream>>>(x, w, xp, bias, out);
    } else {
        simlinear_mfma<false><<<NWG, 256, 0, stream>>>(x, w, xp, bias, out);
    }
}